// Round 13
// baseline (318.083 us; speedup 1.0000x reference)
//
#include <hip/hip_runtime.h>
#include <hip/hip_fp16.h>

// 3-layer gather-GEMM GNN (N=262144, K=8, 16->128->128->16), f16 MFMA.
// Round 13:
//  1) layer1p: __syncthreads() -> block_sync_lds() (s_waitcnt lgkmcnt(0) +
//     s_barrier, CK pattern). The compiler's vmcnt(0) drain at each of the 8
//     K-loop barriers was stalling on just-issued nb+2 gathers; LDS ordering
//     only needs lgkmcnt. Global prefetches now stay in flight across
//     barriers.
//  2) prep_edges fused into layer0 (it already loads nbr rows; computes invd
//     from pos gathers and writes it for layer1p/reduce) — one less pass over
//     nbr + one less launch.
// Round-12 factorization retained: P = h2@W2stacked computed in layer1p's
// epilogue; reduce gathers 32 B/edge from P. Scaled messages prescaled by
// 2^-8; epilogue x256 + bias.
//
// Workspace: ws = h1 (64 MiB) + P (64 MiB) = 128 MiB exactly. invd/h16/Wf live
// in d_out scratch; invd is d2d-copied into dead h1 before the reduce (which
// writes d_out).

typedef _Float16 f16x8 __attribute__((ext_vector_type(8)));
typedef float f32x4 __attribute__((ext_vector_type(4)));

#define NNODES 262144

// LDS-only barrier: orders ds_write/ds_read across waves WITHOUT draining
// outstanding global loads (vmcnt). Composable-kernel's block_sync_lds().
__device__ __forceinline__ void block_sync_lds() {
    asm volatile("s_waitcnt lgkmcnt(0)\n\ts_barrier" ::: "memory");
}

__global__ __launch_bounds__(256) void conv_h_kernel(const float* __restrict__ h,
                                                     __half* __restrict__ h16, int n) {
    int i = blockIdx.x * 256 + threadIdx.x;
    if (i < n) h16[i] = __float2half(h[i]);
}

// Pre-shuffle W [KT][FO] (row-major f32) into MFMA B-fragment order:
// Wf[((s*NT + t)*64 + lane)*8 + j] = W[s*32 + (lane>>4)*8 + j][t*16 + (lane&15)]
__global__ __launch_bounds__(256) void shuffle_w_kernel(const float* __restrict__ W,
                                                        __half* __restrict__ Wf,
                                                        int KT, int FO) {
    int e = blockIdx.x * 256 + threadIdx.x;
    if (e >= KT * FO) return;
    int j = e & 7;
    int lane = (e >> 3) & 63;
    int rest = e >> 9;
    int NT = FO >> 4;
    int t = rest % NT;
    int s = rest / NT;
    int k = s * 32 + (lane >> 4) * 8 + j;
    int n = t * 16 + (lane & 15);
    Wf[e] = __float2half(W[k * FO + n]);
}

// Fragment-order for the STACKED W2: W2s[k][t*16+c] = W2[t*128+k][c]
// (W2 row-major [1024][16]; KT=128, FO=128 -> NT=8).
__global__ __launch_bounds__(256) void shuffle_w2s_kernel(const float* __restrict__ W2,
                                                          __half* __restrict__ Wf) {
    int e = blockIdx.x * 256 + threadIdx.x;
    if (e >= 128 * 128) return;
    int j = e & 7;
    int lane = (e >> 3) & 63;
    int rest = e >> 9;
    int t = rest % 8;
    int s = rest / 8;
    int k = s * 32 + (lane >> 4) * 8 + j;
    Wf[e] = __float2half(W2[(size_t)(t * 128 + k) * 16 + (lane & 15)]);
}

// ------- L0: F_IN=16, F_OUT=128, 128 rows/block, fused invd computation ----
__global__ __launch_bounds__(256) void layer0_kernel(
    const __half* __restrict__ hprev, const float* __restrict__ pos,
    const int* __restrict__ nbr, const __half* __restrict__ Wf,
    const float* __restrict__ bias, __half* __restrict__ outp,
    __half* __restrict__ invd_out) {
    __shared__ __align__(16) __half Bs[16384];  // 32 KB weights, staged once

    const int tid = threadIdx.x;
    const int wave = tid >> 6;
    const int lane = tid & 63;
    const int quad = lane >> 4;
    const int lmod = lane & 15;
    const int mbase = blockIdx.x * 128 + wave * 16 + lmod;

    int idx[2][8];
#pragma unroll
    for (int mt = 0; mt < 2; ++mt) {
        const int m = mbase + mt * 64;
        const int4* nrow = (const int4*)(nbr + (size_t)m * 8);
        const int4 iA = nrow[0];
        const int4 iB = nrow[1];
        idx[mt][0] = iA.x; idx[mt][1] = iA.y; idx[mt][2] = iA.z; idx[mt][3] = iA.w;
        idx[mt][4] = iB.x; idx[mt][5] = iB.y; idx[mt][6] = iB.z; idx[mt][7] = iB.w;
    }

    // Fused prep: invd[e] = fp16((1/d)*2^-8), d = |pos[i]-pos[n]| (0 -> 0.5).
    f16x8 invr[2];
#pragma unroll
    for (int mt = 0; mt < 2; ++mt) {
        const int m = mbase + mt * 64;
        const float mx = pos[(size_t)m * 3 + 0];
        const float my = pos[(size_t)m * 3 + 1];
        const float mz = pos[(size_t)m * 3 + 2];
        f16x8 iv;
#pragma unroll
        for (int k = 0; k < 8; ++k) {
            const size_t b = (size_t)idx[mt][k] * 3;
            float dx = mx - pos[b + 0];
            float dy = my - pos[b + 1];
            float dz = mz - pos[b + 2];
            float d = sqrtf(dx * dx + dy * dy + dz * dz);
            if (d == 0.0f) d = 0.5f;
            iv[k] = (_Float16)((1.0f / d) * 0.00390625f);
        }
        invr[mt] = iv;
        *(f16x8*)(invd_out + (size_t)m * 8) = iv;
    }

    f32x4 acc[2][8];
#pragma unroll
    for (int mt = 0; mt < 2; ++mt)
#pragma unroll
        for (int t = 0; t < 8; ++t) acc[mt][t] = f32x4{0.f, 0.f, 0.f, 0.f};

    {
        const uint4* src = (const uint4*)Wf;
        uint4* dst = (uint4*)Bs;
#pragma unroll
        for (int i = 0; i < 8; ++i) dst[i * 256 + tid] = src[i * 256 + tid];
    }
    block_sync_lds();

#pragma unroll
    for (int s = 0; s < 4; ++s) {
        const int nb = 2 * s + (quad >> 1);
        f16x8 as[2];
#pragma unroll
        for (int mt = 0; mt < 2; ++mt) {
            f16x8 av = *(const f16x8*)(hprev + (size_t)idx[mt][nb] * 16 + (quad & 1) * 8);
            as[mt] = av * invr[mt][nb];
        }
#pragma unroll
        for (int t = 0; t < 8; ++t) {
            f16x8 b = *(const f16x8*)(Bs + ((size_t)(s * 8 + t) * 64 + lane) * 8);
#pragma unroll
            for (int mt = 0; mt < 2; ++mt)
                acc[mt][t] = __builtin_amdgcn_mfma_f32_16x16x32_f16(as[mt], b, acc[mt][t], 0, 0, 0);
        }
    }

#pragma unroll
    for (int mt = 0; mt < 2; ++mt) {
        const int rbase = blockIdx.x * 128 + mt * 64 + wave * 16 + quad * 4;
#pragma unroll
        for (int t = 0; t < 8; ++t) {
            const int col = t * 16 + lmod;
            const float bv = bias[col];
#pragma unroll
            for (int rr = 0; rr < 4; ++rr) {
                float v = acc[mt][t][rr] * 256.0f + bv;
                outp[(size_t)(rbase + rr) * 128 + col] = __float2half(v);
            }
        }
    }
}

// ------- L1+P: F_IN=128, F_OUT=128, 64 rows/block, fused P projection -------
// LDS: seg-major + XOR swizzle, 16B granules: off16(seg,row) =
//   seg*64 + (row & ~15) + ((row ^ seg) & 15)   -> spans [0, 1024) granules.
__device__ __forceinline__ int off16(int seg, int row) {
    return seg * 64 + (row & ~15) + ((row ^ seg) & 15);
}

__global__ __launch_bounds__(256, 3) void layer1p_kernel(
    const __half* __restrict__ hprev, const __half* __restrict__ invd,
    const int* __restrict__ nbr, const __half* __restrict__ Wf,
    const __half* __restrict__ Wf2s, const float* __restrict__ bias,
    __half* __restrict__ Pout) {
    __shared__ __align__(16) __half As[2][8192];  // 2 x 1024 granules x 16B = 32 KB

    const int tid = threadIdx.x;
    const int wave = tid >> 6;
    const int lane = tid & 63;
    const int quad = lane >> 4;
    const int lmod = lane & 15;
    const int rowblk = blockIdx.x * 64;
    const int seg = lmod;  // staging: this thread's 16B segment

    int srow[4], grow_[4], soff[4];
#pragma unroll
    for (int i = 0; i < 4; ++i) {
        srow[i] = wave * 16 + i * 4 + quad;
        grow_[i] = rowblk + srow[i];
        soff[i] = off16(seg, srow[i]) * 8;  // halves
    }

    f16x8 invS[4];
#pragma unroll
    for (int i = 0; i < 4; ++i) invS[i] = *(const f16x8*)(invd + (size_t)grow_[i] * 8);

    // Direct idx for nb0/nb1; 2-slot ring for nb>=2 (idxR[nb&1] = idx(nb+2)).
    int idxA[4], idxB[4], idxR[2][4];
#pragma unroll
    for (int i = 0; i < 4; ++i) {
        idxA[i] = nbr[(size_t)grow_[i] * 8 + 0];
        idxB[i] = nbr[(size_t)grow_[i] * 8 + 1];
        idxR[0][i] = nbr[(size_t)grow_[i] * 8 + 2];
        idxR[1][i] = nbr[(size_t)grow_[i] * 8 + 3];
    }

    // This wave's two output col-tiles: t = wave*2 + tl.
    const __half* WfB = Wf + ((size_t)(wave * 2) * 64 + lane) * 8;

    f16x8 Bc[4][2], Bn[4][2];
#pragma unroll
    for (int ks = 0; ks < 4; ++ks)
#pragma unroll
        for (int tl = 0; tl < 2; ++tl)
            Bc[ks][tl] = *(const f16x8*)(WfB + (size_t)(ks * 8 + tl) * 512);

    // Fragment-read offsets (halves): seg=ks*4+quad, row=m*16+lmod.
    int roff[4][4];
#pragma unroll
    for (int m = 0; m < 4; ++m)
#pragma unroll
        for (int ks = 0; ks < 4; ++ks)
            roff[m][ks] = off16(ks * 4 + quad, m * 16 + lmod) * 8;

    // 2-deep gather ping-pong.
    f16x8 ga[2][4];
#pragma unroll
    for (int i = 0; i < 4; ++i)
        ga[0][i] = *(const f16x8*)(hprev + (size_t)idxA[i] * 128 + seg * 8);
#pragma unroll
    for (int i = 0; i < 4; ++i)
        ga[1][i] = *(const f16x8*)(hprev + (size_t)idxB[i] * 128 + seg * 8);

#pragma unroll
    for (int i = 0; i < 4; ++i) {
        f16x8 v = ga[0][i] * invS[i][0];
        *(f16x8*)(&As[0][soff[i]]) = v;
    }
    block_sync_lds();

    f32x4 acc[4][2];
#pragma unroll
    for (int m = 0; m < 4; ++m) { acc[m][0] = f32x4{0.f,0.f,0.f,0.f}; acc[m][1] = f32x4{0.f,0.f,0.f,0.f}; }

#pragma unroll
    for (int nb = 0; nb < 8; ++nb) {
        const int cur = nb & 1;
        if (nb < 6) {
#pragma unroll
            for (int i = 0; i < 4; ++i)
                ga[cur][i] = *(const f16x8*)(hprev + (size_t)idxR[cur][i] * 128 + seg * 8);
        }
        if (nb < 4) {
#pragma unroll
            for (int i = 0; i < 4; ++i)
                idxR[cur][i] = nbr[(size_t)grow_[i] * 8 + nb + 4];
        }
        if (nb < 7) {
#pragma unroll
            for (int ks = 0; ks < 4; ++ks)
#pragma unroll
                for (int tl = 0; tl < 2; ++tl)
                    Bn[ks][tl] = *(const f16x8*)(WfB + (size_t)(((nb + 1) * 4 + ks) * 8 + tl) * 512);
        }
#pragma unroll
        for (int m = 0; m < 4; ++m) {
#pragma unroll
            for (int ks = 0; ks < 4; ++ks) {
                f16x8 a = *(const f16x8*)(&As[cur][roff[m][ks]]);
                acc[m][0] = __builtin_amdgcn_mfma_f32_16x16x32_f16(a, Bc[ks][0], acc[m][0], 0, 0, 0);
                acc[m][1] = __builtin_amdgcn_mfma_f32_16x16x32_f16(a, Bc[ks][1], acc[m][1], 0, 0, 0);
            }
        }
        if (nb < 7) {
#pragma unroll
            for (int i = 0; i < 4; ++i) {
                f16x8 v = ga[(nb + 1) & 1][i] * invS[i][nb + 1];
                *(f16x8*)(&As[cur ^ 1][soff[i]]) = v;
            }
#pragma unroll
            for (int ks = 0; ks < 4; ++ks) { Bc[ks][0] = Bn[ks][0]; Bc[ks][1] = Bn[ks][1]; }
            block_sync_lds();
        }
    }

    // ---- Fused epilogue: h2 = leaky(acc*256 + b1) -> LDS (swizzled) ----
    __half* As0 = &As[0][0];
#pragma unroll
    for (int m = 0; m < 4; ++m) {
#pragma unroll
        for (int tl = 0; tl < 2; ++tl) {
            const int col = wave * 32 + tl * 16 + lmod;
            const float bv = bias[col];
            const int sg = col >> 3;
            const int jj = col & 7;
#pragma unroll
            for (int rr = 0; rr < 4; ++rr) {
                const int row = m * 16 + quad * 4 + rr;
                float v = acc[m][tl][rr] * 256.0f + bv;
                v = (v >= 0.f) ? v : 0.01f * v;
                As0[off16(sg, row) * 8 + jj] = __float2half(v);
            }
        }
    }
    block_sync_lds();

    // ---- P = h2 @ W2s (K=128, 4 k-steps); wave owns col-tiles wave*2+tl ----
    const __half* WfB2 = Wf2s + ((size_t)(wave * 2) * 64 + lane) * 8;
    f16x8 B2[4][2];
#pragma unroll
    for (int ks = 0; ks < 4; ++ks)
#pragma unroll
        for (int tl = 0; tl < 2; ++tl)
            B2[ks][tl] = *(const f16x8*)(WfB2 + (size_t)(ks * 8 + tl) * 512);

    f32x4 acc2[4][2];
#pragma unroll
    for (int m = 0; m < 4; ++m) { acc2[m][0] = f32x4{0.f,0.f,0.f,0.f}; acc2[m][1] = f32x4{0.f,0.f,0.f,0.f}; }
#pragma unroll
    for (int m = 0; m < 4; ++m) {
#pragma unroll
        for (int ks = 0; ks < 4; ++ks) {
            f16x8 a2 = *(const f16x8*)(&As0[roff[m][ks]]);
            acc2[m][0] = __builtin_amdgcn_mfma_f32_16x16x32_f16(a2, B2[ks][0], acc2[m][0], 0, 0, 0);
            acc2[m][1] = __builtin_amdgcn_mfma_f32_16x16x32_f16(a2, B2[ks][1], acc2[m][1], 0, 0, 0);
        }
    }

    // ---- write P (fp16, true scale) ----
#pragma unroll
    for (int m = 0; m < 4; ++m) {
#pragma unroll
        for (int tl = 0; tl < 2; ++tl) {
            const int col = wave * 32 + tl * 16 + lmod;
#pragma unroll
            for (int rr = 0; rr < 4; ++rr) {
                const int grow = rowblk + m * 16 + quad * 4 + rr;
                Pout[(size_t)grow * 128 + col] = __float2half(acc2[m][tl][rr]);
            }
        }
    }
}

// ---------------- Reduce: out[i] = 256*sum_k invd[i,k]*P[nbr[i,k]][k*16..]+b2
__global__ __launch_bounds__(256) void reduce_kernel(
    const __half* __restrict__ P, const __half* __restrict__ invd,
    const int* __restrict__ nbr, const float* __restrict__ b2,
    float* __restrict__ outp) {
    const int d = blockIdx.x * 256 + threadIdx.x;

    const int4* nrow = (const int4*)(nbr + (size_t)d * 8);
    const int4 iA = nrow[0];
    const int4 iB = nrow[1];
    const int idx[8] = {iA.x, iA.y, iA.z, iA.w, iB.x, iB.y, iB.z, iB.w};
    const f16x8 iv = *(const f16x8*)(invd + (size_t)d * 8);

    f16x8 lo[8], hi[8];
#pragma unroll
    for (int k = 0; k < 8; ++k) {
        const __half* p = P + (size_t)idx[k] * 128 + k * 16;
        lo[k] = *(const f16x8*)p;
        hi[k] = *(const f16x8*)(p + 8);
    }

    float acc[16];
#pragma unroll
    for (int c = 0; c < 16; ++c) acc[c] = 0.f;
#pragma unroll
    for (int k = 0; k < 8; ++k) {
        const float w = (float)iv[k];
#pragma unroll
        for (int c = 0; c < 8; ++c) {
            acc[c] += w * (float)lo[k][c];
            acc[c + 8] += w * (float)hi[k][c];
        }
    }

    float4 o[4];
#pragma unroll
    for (int q = 0; q < 4; ++q) {
        o[q].x = acc[q * 4 + 0] * 256.0f + b2[q * 4 + 0];
        o[q].y = acc[q * 4 + 1] * 256.0f + b2[q * 4 + 1];
        o[q].z = acc[q * 4 + 2] * 256.0f + b2[q * 4 + 2];
        o[q].w = acc[q * 4 + 3] * 256.0f + b2[q * 4 + 3];
    }
    float4* dst = (float4*)(outp + (size_t)d * 16);
#pragma unroll
    for (int q = 0; q < 4; ++q) dst[q] = o[q];
}

extern "C" void kernel_launch(void* const* d_in, const int* in_sizes, int n_in,
                              void* d_out, int out_size, void* d_ws, size_t ws_size,
                              hipStream_t stream) {
    const float* h   = (const float*)d_in[0];
    const float* pos = (const float*)d_in[1];
    const int*   nbr = (const int*)d_in[2];
    const float* W0  = (const float*)d_in[3];
    const float* b0  = (const float*)d_in[4];
    const float* W1  = (const float*)d_in[5];
    const float* b1  = (const float*)d_in[6];
    const float* W2  = (const float*)d_in[7];
    const float* b2  = (const float*)d_in[8];

    const int N = NNODES;

    // ws: h1 (64 MiB) + P (64 MiB) = 128 MiB exactly.
    char* w = (char*)d_ws;
    __half* h1 = (__half*)w;                               // 67,108,864 B
    __half* P  = (__half*)(w + (size_t)67108864);          // 67,108,864 B
    __half* invd2 = (__half*)w;                            // 4 MiB, into dead h1

    // d_out doubles as scratch until reduce overwrites all of it (16 MiB).
    char* ob = (char*)d_out;
    __half* invd = (__half*)(ob + 0);                      // 4,194,304 B
    __half* h16  = (__half*)(ob + 4194304);                // 8,388,608 B
    __half* W0f  = (__half*)(ob + 12582912);               // 32,768 B
    __half* W1f  = (__half*)(ob + 12615680);               // 262,144 B
    __half* Wf2s = (__half*)(ob + 12877824);               // 32,768 B (end 12,910,592)

    conv_h_kernel<<<(N * 16 + 255) / 256, 256, 0, stream>>>(h, h16, N * 16);
    shuffle_w_kernel<<<(128 * 128 + 255) / 256, 256, 0, stream>>>(W0, W0f, 128, 128);
    shuffle_w_kernel<<<(1024 * 128 + 255) / 256, 256, 0, stream>>>(W1, W1f, 1024, 128);
    shuffle_w2s_kernel<<<(128 * 128 + 255) / 256, 256, 0, stream>>>(W2, Wf2s);

    layer0_kernel<<<N / 128, 256, 0, stream>>>(h16, pos, nbr, W0f, b0, h1, invd);
    layer1p_kernel<<<N / 64, 256, 0, stream>>>(h1, invd, nbr, W1f, Wf2s, b1, P);

    // h1 is dead now; move invd out of d_out before reduce writes d_out.
    (void)hipMemcpyAsync(invd2, invd, 4194304, hipMemcpyDeviceToDevice, stream);

    reduce_kernel<<<N / 256, 256, 0, stream>>>(P, invd2, nbr, b2, (float*)d_out);
}